// Round 1
// baseline (337.835 us; speedup 1.0000x reference)
//
#include <hip/hip_runtime.h>

// Problem constants (B=2,S=4096,H=32,P=64,N=64,BLOCK=64)
#define B_ 2
#define S_ 4096
#define H_ 32
#define P_ 64
#define N_ 64
#define C_ 64
#define HP 2048   // H_*P_ : element stride per sequence step in X/Y
#define HN 2048   // H_*N_ : element stride per sequence step in Bm/Cm

typedef __attribute__((ext_vector_type(8))) short bf16x8;
typedef __attribute__((ext_vector_type(4))) float f32x4;

__device__ __forceinline__ float bf2f(unsigned int u16) {
    return __uint_as_float(u16 << 16);
}
__device__ __forceinline__ void unpack2(unsigned int u, float& lo, float& hi) {
    lo = __uint_as_float(u << 16);
    hi = __uint_as_float(u & 0xffff0000u);
}
__device__ __forceinline__ unsigned short f2bf(float f) {
    unsigned int u = __float_as_uint(f);
    u += 0x7fffu + ((u >> 16) & 1u);   // round-to-nearest-even
    return (unsigned short)(u >> 16);
}

// Swizzled byte addresses inside a 64x64 ushort tile (row stride 128 B).
// nsw: natural tiles (coalesced b128 writes / frag reads, both swizzled).
// tsw: transposed tiles (scalar u16 scatter writes vary row-high bits,
//      frag reads vary row-low bits -> XOR both into bank bits).
__device__ __forceinline__ int nsw(int r, int cb) {
    return (r << 7) + (cb ^ ((r & 7) << 4));
}
__device__ __forceinline__ int tsw(int r, int cb) {
    return (r << 7) + (cb ^ ((((r & 7) ^ (r >> 3)) & 7) << 4));
}

// ---------------------------------------------------------------------------
// K0: dtype detection (unchanged). flag=1 -> fp32 inputs.
// ---------------------------------------------------------------------------
__global__ void k0_detect(const unsigned short* __restrict__ Au, int* __restrict__ flag)
{
    int tid = threadIdx.x;              // 64 threads
    unsigned short u = Au[tid * 2];
    int positive = ((u & 0x8000u) == 0) ? 1 : 0;
    unsigned long long m = __ballot(positive);
    if (tid == 0) *flag = (__popcll(m) > 8) ? 1 : 0;
}

// ---------------------------------------------------------------------------
// K1 (bf16/MFMA): states_pn[p][n] = sum_t X[t][p] * (wdec[t]*B[t][n])
// MFMA: A = X^T (rows p, k=t), B = Bw (k=t, cols n). Both staged t-contiguous
// (transposed, tsw). Output stored [p][n] fp32 (k2 is layout-agnostic).
// ---------------------------------------------------------------------------
__global__ __launch_bounds__(256) void k1b(
    const unsigned short* __restrict__ Xg,
    const unsigned short* __restrict__ Ag,
    const unsigned short* __restrict__ Bg,
    float* __restrict__ states,
    float* __restrict__ sums,
    const int* __restrict__ flag)
{
    if (*flag) return;
    __shared__ __align__(16) unsigned short XT[64 * 64];  // [p][t] tsw
    __shared__ __align__(16) unsigned short BT[64 * 64];  // [n][t] tsw, decay-weighted
    __shared__ float wdec[64];

    const int tid = threadIdx.x;
    const int bid = blockIdx.x;
    const int h = bid & 31, c = (bid >> 5) & 63, b = bid >> 11;

    if (tid < 64) {
        int ai = (b * S_ + c * 64 + tid) * H_ + h;
        float a = bf2f(Ag[ai]);
        float x = a;
        #pragma unroll
        for (int off = 1; off < 64; off <<= 1) {
            float y = __shfl_up(x, off, 64);
            if (tid >= off) x += y;
        }
        float tot = __shfl(x, 63, 64);
        wdec[tid] = __expf(tot - x);
        if (tid == 63) sums[(b * H_ + h) * C_ + c] = tot;
    }
    __syncthreads();

    const size_t baseX = (size_t)((b * S_ + c * 64) * H_ + h) * P_;
    const size_t baseB = (size_t)((b * S_ + c * 64) * H_ + h) * N_;
    const unsigned short* Xp = Xg + baseX;
    const unsigned short* Bp = Bg + baseB;
    char* XTb = (char*)XT;
    char* BTb = (char*)BT;

    #pragma unroll
    for (int it = 0; it < 2; ++it) {
        int t = (tid >> 3) + it * 32;
        int e = (tid & 7) * 8;
        uint4 rx = *(const uint4*)(Xp + (size_t)t * HP + e);
        const unsigned short* xs = (const unsigned short*)&rx;
        #pragma unroll
        for (int i = 0; i < 8; ++i)
            *(unsigned short*)(XTb + tsw(e + i, 2 * t)) = xs[i];

        uint4 rb = *(const uint4*)(Bp + (size_t)t * HN + e);
        float w = wdec[t];
        float v0, v1, v2, v3, v4, v5, v6, v7;
        unpack2(rb.x, v0, v1); unpack2(rb.y, v2, v3);
        unpack2(rb.z, v4, v5); unpack2(rb.w, v6, v7);
        unsigned short bs0 = f2bf(v0 * w), bs1 = f2bf(v1 * w);
        unsigned short bs2 = f2bf(v2 * w), bs3 = f2bf(v3 * w);
        unsigned short bs4 = f2bf(v4 * w), bs5 = f2bf(v5 * w);
        unsigned short bs6 = f2bf(v6 * w), bs7 = f2bf(v7 * w);
        *(unsigned short*)(BTb + tsw(e + 0, 2 * t)) = bs0;
        *(unsigned short*)(BTb + tsw(e + 1, 2 * t)) = bs1;
        *(unsigned short*)(BTb + tsw(e + 2, 2 * t)) = bs2;
        *(unsigned short*)(BTb + tsw(e + 3, 2 * t)) = bs3;
        *(unsigned short*)(BTb + tsw(e + 4, 2 * t)) = bs4;
        *(unsigned short*)(BTb + tsw(e + 5, 2 * t)) = bs5;
        *(unsigned short*)(BTb + tsw(e + 6, 2 * t)) = bs6;
        *(unsigned short*)(BTb + tsw(e + 7, 2 * t)) = bs7;
    }
    __syncthreads();

    const int l = tid & 63, w4 = tid >> 6;
    const int lr = l & 15, q = l >> 4;

    bf16x8 a0 = *(const bf16x8*)(XTb + tsw(16 * w4 + lr, 16 * q));
    bf16x8 a1 = *(const bf16x8*)(XTb + tsw(16 * w4 + lr, 16 * q + 64));
    f32x4 acc[4];
    #pragma unroll
    for (int nt = 0; nt < 4; ++nt) acc[nt] = (f32x4){0.f, 0.f, 0.f, 0.f};
    #pragma unroll
    for (int nt = 0; nt < 4; ++nt) {
        bf16x8 b0 = *(const bf16x8*)(BTb + tsw(16 * nt + lr, 16 * q));
        acc[nt] = __builtin_amdgcn_mfma_f32_16x16x32_bf16(a0, b0, acc[nt], 0, 0, 0);
        bf16x8 b1 = *(const bf16x8*)(BTb + tsw(16 * nt + lr, 16 * q + 64));
        acc[nt] = __builtin_amdgcn_mfma_f32_16x16x32_bf16(a1, b1, acc[nt], 0, 0, 0);
    }

    float* sp = states + (size_t)((b * C_ + c) * H_ + h) * 4096;
    #pragma unroll
    for (int nt = 0; nt < 4; ++nt)
        #pragma unroll
        for (int r = 0; r < 4; ++r) {
            int p = 16 * w4 + 4 * q + r;
            int n = 16 * nt + lr;
            sp[p * 64 + n] = acc[nt][r];
        }
}

// ---------------------------------------------------------------------------
// K1 (fp32 path): original VALU kernel, verbatim, gated on flag==1.
// Writes states in its own [n][p] layout (k3f matches; k2 is agnostic).
// ---------------------------------------------------------------------------
__global__ __launch_bounds__(256) void k1f(
    const void* __restrict__ Xg,
    const void* __restrict__ Ag,
    const void* __restrict__ Bg,
    float* __restrict__ states,
    float* __restrict__ sums,
    const int* __restrict__ flag)
{
    if (!(*flag)) return;
    __shared__ __align__(16) float Xs[64][68];    // [t][p]
    __shared__ __align__(16) float BwT[64][68];   // [n][t], pre-scaled by decay
    __shared__ float wdec[64];

    const int tid = threadIdx.x;
    const int bid = blockIdx.x;
    const int h = bid & 31;
    const int c = (bid >> 5) & 63;
    const int b = bid >> 11;

    if (tid < 64) {
        int ai = (b * S_ + c * 64 + tid) * H_ + h;
        float a = ((const float*)Ag)[ai];
        float x = a;
        #pragma unroll
        for (int off = 1; off < 64; off <<= 1) {
            float y = __shfl_up(x, off, 64);
            if (tid >= off) x += y;
        }
        float tot = __shfl(x, 63, 64);
        wdec[tid] = __expf(tot - x);
        if (tid == 63) sums[(b * H_ + h) * C_ + c] = tot;
    }
    __syncthreads();

    const size_t baseX = (size_t)((b * S_ + c * 64) * H_ + h) * P_;
    const size_t baseB = (size_t)((b * S_ + c * 64) * H_ + h) * N_;

    {
        const float* Xp = (const float*)Xg + baseX;
        const float* Bp = (const float*)Bg + baseB;
        #pragma unroll
        for (int it = 0; it < 2; ++it) {
            int f = it * 2048 + tid * 8;
            int t = f >> 6;
            int e = f & 63;
            float4 x0 = *(const float4*)(Xp + (size_t)t * HP + e);
            float4 x1 = *(const float4*)(Xp + (size_t)t * HP + e + 4);
            float* xr = &Xs[t][e];
            xr[0]=x0.x; xr[1]=x0.y; xr[2]=x0.z; xr[3]=x0.w;
            xr[4]=x1.x; xr[5]=x1.y; xr[6]=x1.z; xr[7]=x1.w;

            float4 b0 = *(const float4*)(Bp + (size_t)t * HN + e);
            float4 b1 = *(const float4*)(Bp + (size_t)t * HN + e + 4);
            float w = wdec[t];
            BwT[e+0][t]=b0.x*w; BwT[e+1][t]=b0.y*w; BwT[e+2][t]=b0.z*w; BwT[e+3][t]=b0.w*w;
            BwT[e+4][t]=b1.x*w; BwT[e+5][t]=b1.y*w; BwT[e+6][t]=b1.z*w; BwT[e+7][t]=b1.w*w;
        }
    }
    __syncthreads();

    const int tr = tid >> 4, tc = tid & 15;
    float acc[4][4];
    #pragma unroll
    for (int i = 0; i < 4; ++i)
        #pragma unroll
        for (int j = 0; j < 4; ++j) acc[i][j] = 0.f;

    #pragma unroll 4
    for (int k4 = 0; k4 < 16; ++k4) {
        float la[4][4];
        #pragma unroll
        for (int i = 0; i < 4; ++i) {
            float4 v = *(const float4*)&BwT[tr * 4 + i][k4 * 4];
            la[i][0]=v.x; la[i][1]=v.y; la[i][2]=v.z; la[i][3]=v.w;
        }
        #pragma unroll
        for (int kk = 0; kk < 4; ++kk) {
            float4 r = *(const float4*)&Xs[k4 * 4 + kk][tc * 4];
            #pragma unroll
            for (int i = 0; i < 4; ++i) {
                acc[i][0] += la[i][kk] * r.x;
                acc[i][1] += la[i][kk] * r.y;
                acc[i][2] += la[i][kk] * r.z;
                acc[i][3] += la[i][kk] * r.w;
            }
        }
    }

    float* sp = states + (size_t)((b * C_ + c) * H_ + h) * 4096;
    #pragma unroll
    for (int i = 0; i < 4; ++i) {
        float4 v; v.x=acc[i][0]; v.y=acc[i][1]; v.z=acc[i][2]; v.w=acc[i][3];
        *(float4*)&sp[(tr * 4 + i) * 64 + tc * 4] = v;
    }
}

// ---------------------------------------------------------------------------
// K2: inter-chunk scan, in place. 512 blocks (2/CU, 8 waves/CU), float2
// chains, explicit next-chunk prefetch to break the load->latency serial
// chain. Layout-agnostic across the 4096 state elements.
// ---------------------------------------------------------------------------
__global__ __launch_bounds__(256) void k2_scan(
    float* __restrict__ states, const float* __restrict__ sums)
{
    const int tid = threadIdx.x;
    const int bid = blockIdx.x;
    const int split = bid & 7;
    const int bh = bid >> 3;
    const int h = bh & 31;
    const int b = bh >> 5;
    const int e = split * 512 + tid * 2;
    const float* sm = sums + (b * H_ + h) * C_;
    const size_t cstride = (size_t)H_ * 4096;
    float* p = states + ((size_t)(b * C_) * H_ + h) * 4096 + e;
    float2 S = make_float2(0.f, 0.f);
    float2 st = *(const float2*)p;
    #pragma unroll 4
    for (int c = 0; c < 64; ++c) {
        float2 stn = make_float2(0.f, 0.f);
        if (c < 63) stn = *(const float2*)(p + cstride);   // prefetch next chunk
        float d = __expf(sm[c]);
        *(float2*)p = S;          // S_enter[c]
        S.x = S.x * d + st.x;
        S.y = S.y * d + st.y;
        st = stn;
        p += cstride;
    }
}

// ---------------------------------------------------------------------------
// K3 (bf16/MFMA):
//   MFMA#1: M = C·B^T  (contract n; both operands natural [t][n], nsw)
//   mask+decay in-register -> M bf16 into Bs region as [t][s]
//   MFMA#2: Y += M·X    (contract s; X transposed to [p][s], tsw)
//   MFMA#3: Y += (C·e^{cs[t]})·S  (contract n; states staged [p][n], nsw;
//           row scale folded into the A fragment registers)
// ---------------------------------------------------------------------------
__global__ __launch_bounds__(256) void k3b(
    const unsigned short* __restrict__ Xg,
    const unsigned short* __restrict__ Ag,
    const unsigned short* __restrict__ Bg,
    const unsigned short* __restrict__ Cg,
    const float* __restrict__ states,
    unsigned short* __restrict__ Yg,
    const int* __restrict__ flag)
{
    if (*flag) return;
    __shared__ __align__(16) unsigned short Cs[64 * 64]; // [t][n] nsw
    __shared__ __align__(16) unsigned short Bs[64 * 64]; // [s][n] nsw; reused as M [t][s]
    __shared__ __align__(16) unsigned short XT[64 * 64]; // [p][s] tsw
    __shared__ __align__(16) unsigned short Ss[64 * 64]; // [p][n] nsw
    __shared__ float csh[64];

    const int tid = threadIdx.x;
    const int bid = blockIdx.x;
    const int h = bid & 31, c = (bid >> 5) & 63, b = bid >> 11;

    if (tid < 64) {
        int ai = (b * S_ + c * 64 + tid) * H_ + h;
        float a = bf2f(Ag[ai]);
        float x = a;
        #pragma unroll
        for (int off = 1; off < 64; off <<= 1) {
            float y = __shfl_up(x, off, 64);
            if (tid >= off) x += y;
        }
        csh[tid] = x;
    }

    const size_t baseX = (size_t)((b * S_ + c * 64) * H_ + h) * P_;
    const size_t baseN = (size_t)((b * S_ + c * 64) * H_ + h) * N_;
    const unsigned short* Xp = Xg + baseX;
    const unsigned short* Bp = Bg + baseN;
    const unsigned short* Cp = Cg + baseN;
    char* Csb = (char*)Cs;
    char* Bsb = (char*)Bs;
    char* XTb = (char*)XT;
    char* Ssb = (char*)Ss;

    #pragma unroll
    for (int it = 0; it < 2; ++it) {
        int t = (tid >> 3) + it * 32;
        int e = (tid & 7) * 8;
        uint4 rc = *(const uint4*)(Cp + (size_t)t * HN + e);
        *(uint4*)(Csb + nsw(t, 2 * e)) = rc;
        uint4 rb = *(const uint4*)(Bp + (size_t)t * HN + e);
        *(uint4*)(Bsb + nsw(t, 2 * e)) = rb;
        uint4 rx = *(const uint4*)(Xp + (size_t)t * HP + e);
        const unsigned short* xs = (const unsigned short*)&rx;
        #pragma unroll
        for (int i = 0; i < 8; ++i)
            *(unsigned short*)(XTb + tsw(e + i, 2 * t)) = xs[i];
    }
    {
        const float* sb = states + (size_t)((b * C_ + c) * H_ + h) * 4096;
        #pragma unroll
        for (int k = 0; k < 4; ++k) {
            int e2 = (k * 256 + tid) * 4;
            float4 v = *(const float4*)(sb + e2);
            uint2 u;
            u.x = (unsigned int)f2bf(v.x) | ((unsigned int)f2bf(v.y) << 16);
            u.y = (unsigned int)f2bf(v.z) | ((unsigned int)f2bf(v.w) << 16);
            *(uint2*)(Ssb + nsw(e2 >> 6, 2 * (e2 & 63))) = u;
        }
    }
    __syncthreads();

    const int l = tid & 63, w4 = tid >> 6;
    const int lr = l & 15, q = l >> 4;
    const int tA = 16 * w4 + lr;     // this lane's A-fragment row (t)

    bf16x8 ac0 = *(const bf16x8*)(Csb + nsw(tA, 16 * q));
    bf16x8 ac1 = *(const bf16x8*)(Csb + nsw(tA, 16 * q + 64));

    // MFMA#1: M = C·B^T
    f32x4 mac[4];
    #pragma unroll
    for (int st = 0; st < 4; ++st) mac[st] = (f32x4){0.f, 0.f, 0.f, 0.f};
    #pragma unroll
    for (int st = 0; st < 4; ++st) {
        bf16x8 b0 = *(const bf16x8*)(Bsb + nsw(16 * st + lr, 16 * q));
        mac[st] = __builtin_amdgcn_mfma_f32_16x16x32_bf16(ac0, b0, mac[st], 0, 0, 0);
        bf16x8 b1 = *(const bf16x8*)(Bsb + nsw(16 * st + lr, 16 * q + 64));
        mac[st] = __builtin_amdgcn_mfma_f32_16x16x32_bf16(ac1, b1, mac[st], 0, 0, 0);
    }
    __syncthreads();   // all waves done reading Bs

    // mask + segment decay; store M (bf16) into Bs region as [t][s]
    #pragma unroll
    for (int st = 0; st < 4; ++st) {
        int s = 16 * st + lr;
        float cs_s = csh[s];
        #pragma unroll
        for (int r = 0; r < 4; ++r) {
            int t = 16 * w4 + 4 * q + r;
            float v = (s <= t) ? mac[st][r] * __expf(csh[t] - cs_s) : 0.f;
            *(unsigned short*)(Bsb + nsw(t, 2 * s)) = f2bf(v);
        }
    }
    __syncthreads();

    // MFMA#2 + #3 accumulate into the same Y accumulator
    f32x4 yac[4];
    #pragma unroll
    for (int pt = 0; pt < 4; ++pt) yac[pt] = (f32x4){0.f, 0.f, 0.f, 0.f};

    bf16x8 am0 = *(const bf16x8*)(Bsb + nsw(tA, 16 * q));
    bf16x8 am1 = *(const bf16x8*)(Bsb + nsw(tA, 16 * q + 64));
    #pragma unroll
    for (int pt = 0; pt < 4; ++pt) {
        bf16x8 x0 = *(const bf16x8*)(XTb + tsw(16 * pt + lr, 16 * q));
        yac[pt] = __builtin_amdgcn_mfma_f32_16x16x32_bf16(am0, x0, yac[pt], 0, 0, 0);
        bf16x8 x1 = *(const bf16x8*)(XTb + tsw(16 * pt + lr, 16 * q + 64));
        yac[pt] = __builtin_amdgcn_mfma_f32_16x16x32_bf16(am1, x1, yac[pt], 0, 0, 0);
    }

    // scale C rows by exp(cs[t]) in-register (keeps exp factors fp32-exact)
    float g = __expf(csh[tA]);
    bf16x8 as0, as1;
    #pragma unroll
    for (int i = 0; i < 8; ++i) {
        as0[i] = (short)f2bf(bf2f((unsigned short)ac0[i]) * g);
        as1[i] = (short)f2bf(bf2f((unsigned short)ac1[i]) * g);
    }
    #pragma unroll
    for (int pt = 0; pt < 4; ++pt) {
        bf16x8 s0 = *(const bf16x8*)(Ssb + nsw(16 * pt + lr, 16 * q));
        yac[pt] = __builtin_amdgcn_mfma_f32_16x16x32_bf16(as0, s0, yac[pt], 0, 0, 0);
        bf16x8 s1 = *(const bf16x8*)(Ssb + nsw(16 * pt + lr, 16 * q + 64));
        yac[pt] = __builtin_amdgcn_mfma_f32_16x16x32_bf16(as1, s1, yac[pt], 0, 0, 0);
    }

    // Y[t][p] = yac[pt][r], t = 16*w4 + 4*q + r, p = 16*pt + lr
    unsigned short* Yp = Yg + baseX;
    #pragma unroll
    for (int pt = 0; pt < 4; ++pt)
        #pragma unroll
        for (int r = 0; r < 4; ++r) {
            int t = 16 * w4 + 4 * q + r;
            Yp[(size_t)t * HP + 16 * pt + lr] = f2bf(yac[pt][r]);
        }
}

// ---------------------------------------------------------------------------
// K3 (fp32 path): original VALU kernel, verbatim, gated on flag==1.
// ---------------------------------------------------------------------------
__global__ __launch_bounds__(256) void k3f(
    const void* __restrict__ Xg,
    const void* __restrict__ Ag,
    const void* __restrict__ Bg,
    const void* __restrict__ Cg,
    const float* __restrict__ states,
    void* __restrict__ Yg,
    const int* __restrict__ flag)
{
    if (!(*flag)) return;
    __shared__ __align__(16) float Cs[64][68];   // [t][n]
    __shared__ __align__(16) float Mb[64][68];   // [t][s]
    __shared__ __align__(16) float Rb[64][68];   // B^T[n][s] -> X[s][p] -> S[n][p]
    __shared__ float cs[64];

    const int tid = threadIdx.x;
    const int bid = blockIdx.x;
    const int h = bid & 31;
    const int c = (bid >> 5) & 63;
    const int b = bid >> 11;

    if (tid < 64) {
        int ai = (b * S_ + c * 64 + tid) * H_ + h;
        float a = ((const float*)Ag)[ai];
        float x = a;
        #pragma unroll
        for (int off = 1; off < 64; off <<= 1) {
            float y = __shfl_up(x, off, 64);
            if (tid >= off) x += y;
        }
        cs[tid] = x;
    }

    const size_t baseX = (size_t)((b * S_ + c * 64) * H_ + h) * P_;
    const size_t baseN = (size_t)((b * S_ + c * 64) * H_ + h) * N_;

    {
        const float* Bp = (const float*)Bg + baseN;
        const float* Cp = (const float*)Cg + baseN;
        #pragma unroll
        for (int it = 0; it < 2; ++it) {
            int f = it * 2048 + tid * 8;
            int t = f >> 6;
            int e = f & 63;
            float4 c0 = *(const float4*)(Cp + (size_t)t * HN + e);
            float4 c1 = *(const float4*)(Cp + (size_t)t * HN + e + 4);
            float* cr = &Cs[t][e];
            cr[0]=c0.x; cr[1]=c0.y; cr[2]=c0.z; cr[3]=c0.w;
            cr[4]=c1.x; cr[5]=c1.y; cr[6]=c1.z; cr[7]=c1.w;

            float4 b0 = *(const float4*)(Bp + (size_t)t * HN + e);
            float4 b1 = *(const float4*)(Bp + (size_t)t * HN + e + 4);
            Rb[e+0][t]=b0.x; Rb[e+1][t]=b0.y; Rb[e+2][t]=b0.z; Rb[e+3][t]=b0.w;
            Rb[e+4][t]=b1.x; Rb[e+5][t]=b1.y; Rb[e+6][t]=b1.z; Rb[e+7][t]=b1.w;
        }
    }
    __syncthreads();

    const int tr = tid >> 4, tc = tid & 15;

    {
        float acc[4][4];
        #pragma unroll
        for (int i = 0; i < 4; ++i)
            #pragma unroll
            for (int j = 0; j < 4; ++j) acc[i][j] = 0.f;

        #pragma unroll 4
        for (int k4 = 0; k4 < 16; ++k4) {
            float la[4][4];
            #pragma unroll
            for (int i = 0; i < 4; ++i) {
                float4 v = *(const float4*)&Cs[tr * 4 + i][k4 * 4];
                la[i][0]=v.x; la[i][1]=v.y; la[i][2]=v.z; la[i][3]=v.w;
            }
            #pragma unroll
            for (int kk = 0; kk < 4; ++kk) {
                float4 r = *(const float4*)&Rb[k4 * 4 + kk][tc * 4];
                #pragma unroll
                for (int i = 0; i < 4; ++i) {
                    acc[i][0] += la[i][kk] * r.x;
                    acc[i][1] += la[i][kk] * r.y;
                    acc[i][2] += la[i][kk] * r.z;
                    acc[i][3] += la[i][kk] * r.w;
                }
            }
        }

        float ct[4], csj[4];
        #pragma unroll
        for (int i = 0; i < 4; ++i) ct[i] = cs[tr * 4 + i];
        #pragma unroll
        for (int j = 0; j < 4; ++j) csj[j] = cs[tc * 4 + j];
        #pragma unroll
        for (int i = 0; i < 4; ++i) {
            int t = tr * 4 + i;
            float4 mv;
            mv.x = (tc*4+0 <= t) ? acc[i][0] * __expf(ct[i]-csj[0]) : 0.f;
            mv.y = (tc*4+1 <= t) ? acc[i][1] * __expf(ct[i]-csj[1]) : 0.f;
            mv.z = (tc*4+2 <= t) ? acc[i][2] * __expf(ct[i]-csj[2]) : 0.f;
            mv.w = (tc*4+3 <= t) ? acc[i][3] * __expf(ct[i]-csj[3]) : 0.f;
            *(float4*)&Mb[t][tc * 4] = mv;
        }
    }
    __syncthreads();

    {
        const float* Xp = (const float*)Xg + baseX;
        #pragma unroll
        for (int it = 0; it < 2; ++it) {
            int f = it * 2048 + tid * 8;
            int t = f >> 6;
            int e = f & 63;
            float4 x0 = *(const float4*)(Xp + (size_t)t * HP + e);
            float4 x1 = *(const float4*)(Xp + (size_t)t * HP + e + 4);
            float* xr = &Rb[t][e];
            xr[0]=x0.x; xr[1]=x0.y; xr[2]=x0.z; xr[3]=x0.w;
            xr[4]=x1.x; xr[5]=x1.y; xr[6]=x1.z; xr[7]=x1.w;
        }
    }
    __syncthreads();

    float accD[4][4];
    #pragma unroll
    for (int i = 0; i < 4; ++i)
        #pragma unroll
        for (int j = 0; j < 4; ++j) accD[i][j] = 0.f;

    #pragma unroll 4
    for (int k4 = 0; k4 < 16; ++k4) {
        float la[4][4];
        #pragma unroll
        for (int i = 0; i < 4; ++i) {
            float4 v = *(const float4*)&Mb[tr * 4 + i][k4 * 4];
            la[i][0]=v.x; la[i][1]=v.y; la[i][2]=v.z; la[i][3]=v.w;
        }
        #pragma unroll
        for (int kk = 0; kk < 4; ++kk) {
            float4 r = *(const float4*)&Rb[k4 * 4 + kk][tc * 4];
            #pragma unroll
            for (int i = 0; i < 4; ++i) {
                accD[i][0] += la[i][kk] * r.x;
                accD[i][1] += la[i][kk] * r.y;
                accD[i][2] += la[i][kk] * r.z;
                accD[i][3] += la[i][kk] * r.w;
            }
        }
    }
    __syncthreads();

    {
        const float* sb = states + (size_t)((b * C_ + c) * H_ + h) * 4096;
        #pragma unroll
        for (int k = 0; k < 4; ++k) {
            int e2 = (k * 256 + tid) * 4;
            float4 v = *(const float4*)(sb + e2);
            *(float4*)&Rb[e2 >> 6][e2 & 63] = v;
        }
    }
    __syncthreads();

    float accO[4][4];
    #pragma unroll
    for (int i = 0; i < 4; ++i)
        #pragma unroll
        for (int j = 0; j < 4; ++j) accO[i][j] = 0.f;

    #pragma unroll 4
    for (int k4 = 0; k4 < 16; ++k4) {
        float la[4][4];
        #pragma unroll
        for (int i = 0; i < 4; ++i) {
            float4 v = *(const float4*)&Cs[tr * 4 + i][k4 * 4];
            la[i][0]=v.x; la[i][1]=v.y; la[i][2]=v.z; la[i][3]=v.w;
        }
        #pragma unroll
        for (int kk = 0; kk < 4; ++kk) {
            float4 r = *(const float4*)&Rb[k4 * 4 + kk][tc * 4];
            #pragma unroll
            for (int i = 0; i < 4; ++i) {
                accO[i][0] += la[i][kk] * r.x;
                accO[i][1] += la[i][kk] * r.y;
                accO[i][2] += la[i][kk] * r.z;
                accO[i][3] += la[i][kk] * r.w;
            }
        }
    }

    {
        float* Yp = (float*)Yg + baseX;
        #pragma unroll
        for (int i = 0; i < 4; ++i) {
            int t = tr * 4 + i;
            float g = __expf(cs[t]);
            float4 o;
            o.x = accD[i][0] + g * accO[i][0];
            o.y = accD[i][1] + g * accO[i][1];
            o.z = accD[i][2] + g * accO[i][2];
            o.w = accD[i][3] + g * accO[i][3];
            *(float4*)&Yp[(size_t)t * HP + tc * 4] = o;
        }
    }
}

extern "C" void kernel_launch(void* const* d_in, const int* in_sizes, int n_in,
                              void* d_out, int out_size, void* d_ws, size_t ws_size,
                              hipStream_t stream) {
    const void* X  = d_in[0];
    const void* A  = d_in[1];
    const void* Bm = d_in[2];
    const void* Cm = d_in[3];

    // ws layout: [0..15] flag int (16B), then sums (4096 f), then states (16M f)
    int*   flag   = (int*)d_ws;
    float* sums   = (float*)d_ws + 16;
    float* states = (float*)d_ws + 16 + 4096;

    k0_detect<<<dim3(1), dim3(64), 0, stream>>>((const unsigned short*)A, flag);
    k1b<<<dim3(B_ * C_ * H_), dim3(256), 0, stream>>>(
        (const unsigned short*)X, (const unsigned short*)A,
        (const unsigned short*)Bm, states, sums, flag);
    k1f<<<dim3(B_ * C_ * H_), dim3(256), 0, stream>>>(X, A, Bm, states, sums, flag);
    k2_scan<<<dim3(B_ * H_ * 8), dim3(256), 0, stream>>>(states, sums);
    k3b<<<dim3(B_ * C_ * H_), dim3(256), 0, stream>>>(
        (const unsigned short*)X, (const unsigned short*)A,
        (const unsigned short*)Bm, (const unsigned short*)Cm,
        states, (unsigned short*)d_out, flag);
    k3f<<<dim3(B_ * C_ * H_), dim3(256), 0, stream>>>(X, A, Bm, Cm, states, d_out, flag);
}

// Round 2
// 282.576 us; speedup vs baseline: 1.1956x; 1.1956x over previous
//
#include <hip/hip_runtime.h>

// Problem constants (B=2,S=4096,H=32,P=64,N=64,BLOCK=64)
#define B_ 2
#define S_ 4096
#define H_ 32
#define P_ 64
#define N_ 64
#define C_ 64
#define HP 2048   // H_*P_ : element stride per sequence step in X/Y
#define HN 2048   // H_*N_ : element stride per sequence step in Bm/Cm

typedef __attribute__((ext_vector_type(8))) short bf16x8;
typedef __attribute__((ext_vector_type(4))) float f32x4;

__device__ __forceinline__ float bf2f(unsigned int u16) {
    return __uint_as_float(u16 << 16);
}
__device__ __forceinline__ void unpack2(unsigned int u, float& lo, float& hi) {
    lo = __uint_as_float(u << 16);
    hi = __uint_as_float(u & 0xffff0000u);
}
__device__ __forceinline__ unsigned short f2bf(float f) {
    unsigned int u = __float_as_uint(f);
    u += 0x7fffu + ((u >> 16) & 1u);   // round-to-nearest-even
    return (unsigned short)(u >> 16);
}
// fp32 -> bf16 hi + bf16 lo (x ~= hi + lo, residual ~2^-18 * |x|)
__device__ __forceinline__ void split_bf(float x, unsigned short& h, unsigned short& l) {
    h = f2bf(x);
    l = f2bf(x - bf2f(h));
}

// Swizzled byte addresses inside a 64x64 ushort tile (row stride 128 B).
// nsw: natural tiles (16B writes along the row / 16B frag reads).
// tsw: transposed tiles (scalar u16 scatter writes vary row bits 0..5).
__device__ __forceinline__ int nsw(int r, int cb) {
    return (r << 7) + (cb ^ ((r & 7) << 4));
}
__device__ __forceinline__ int tsw(int r, int cb) {
    return (r << 7) + (cb ^ ((((r & 7) ^ (r >> 3)) & 7) << 4));
}

// ---------------------------------------------------------------------------
// K0: dtype detection. A = -|normal|*0.1 is strictly negative. If data is
// bf16, every even-index ushort has sign bit set. If fp32, even-index
// ushorts are low mantissa halves: ~50% positive. flag=1 -> fp32.
// ---------------------------------------------------------------------------
__global__ void k0_detect(const unsigned short* __restrict__ Au, int* __restrict__ flag)
{
    int tid = threadIdx.x;              // 64 threads
    unsigned short u = Au[tid * 2];
    int positive = ((u & 0x8000u) == 0) ? 1 : 0;
    unsigned long long m = __ballot(positive);
    if (tid == 0) *flag = (__popcll(m) > 8) ? 1 : 0;
}

// ---------------------------------------------------------------------------
// K1 (unified, split-bf16 MFMA):
//   states[p][n] = sum_t X[t][p] * (wdec[t]*B[t][n])
// Operands staged t-contiguous (transposed, tsw) as hi/lo bf16 tiles.
// A = X^T (rows p, k=t), B = Bw^T (rows n, k=t).
// 3-term split product: Ah*Bh + Ah*Bl + Al*Bh  (~fp32 accuracy).
// ---------------------------------------------------------------------------
__global__ __launch_bounds__(256, 4) void k1u(
    const void* __restrict__ Xg,
    const void* __restrict__ Ag,
    const void* __restrict__ Bg,
    float* __restrict__ states,
    float* __restrict__ sums,
    const int* __restrict__ flag)
{
    __shared__ __align__(16) unsigned short XTh[4096];
    __shared__ __align__(16) unsigned short XTl[4096];
    __shared__ __align__(16) unsigned short BTh[4096];
    __shared__ __align__(16) unsigned short BTl[4096];
    __shared__ float wdec[64];

    const int tid = threadIdx.x;
    const int bid = blockIdx.x;
    const int h = bid & 31, c = (bid >> 5) & 63, b = bid >> 11;
    const int isf32 = *flag;

    if (tid < 64) {
        int ai = (b * S_ + c * 64 + tid) * H_ + h;
        float a = isf32 ? ((const float*)Ag)[ai] : bf2f(((const unsigned short*)Ag)[ai]);
        float x = a;
        #pragma unroll
        for (int off = 1; off < 64; off <<= 1) {
            float y = __shfl_up(x, off, 64);
            if (tid >= off) x += y;
        }
        float tot = __shfl(x, 63, 64);
        wdec[tid] = __expf(tot - x);
        if (tid == 63) sums[(b * H_ + h) * C_ + c] = tot;
    }
    __syncthreads();

    const size_t baseX = (size_t)((b * S_ + c * 64) * H_ + h) * P_;
    const size_t baseB = (size_t)((b * S_ + c * 64) * H_ + h) * N_;
    char* XThb = (char*)XTh;
    char* XTlb = (char*)XTl;
    char* BThb = (char*)BTh;
    char* BTlb = (char*)BTl;

    #pragma unroll
    for (int it = 0; it < 2; ++it) {
        int t = (tid >> 3) + it * 32;
        int e = (tid & 7) * 8;
        float xv[8], bv[8];
        if (isf32) {
            const float* Xp = (const float*)Xg + baseX + (size_t)t * HP + e;
            const float* Bp = (const float*)Bg + baseB + (size_t)t * HN + e;
            float4 x0 = *(const float4*)Xp;
            float4 x1 = *(const float4*)(Xp + 4);
            float4 b0 = *(const float4*)Bp;
            float4 b1 = *(const float4*)(Bp + 4);
            xv[0]=x0.x; xv[1]=x0.y; xv[2]=x0.z; xv[3]=x0.w;
            xv[4]=x1.x; xv[5]=x1.y; xv[6]=x1.z; xv[7]=x1.w;
            bv[0]=b0.x; bv[1]=b0.y; bv[2]=b0.z; bv[3]=b0.w;
            bv[4]=b1.x; bv[5]=b1.y; bv[6]=b1.z; bv[7]=b1.w;
        } else {
            const unsigned short* Xp = (const unsigned short*)Xg + baseX + (size_t)t * HP + e;
            const unsigned short* Bp = (const unsigned short*)Bg + baseB + (size_t)t * HN + e;
            uint4 rx = *(const uint4*)Xp;
            uint4 rb = *(const uint4*)Bp;
            unpack2(rx.x, xv[0], xv[1]); unpack2(rx.y, xv[2], xv[3]);
            unpack2(rx.z, xv[4], xv[5]); unpack2(rx.w, xv[6], xv[7]);
            unpack2(rb.x, bv[0], bv[1]); unpack2(rb.y, bv[2], bv[3]);
            unpack2(rb.z, bv[4], bv[5]); unpack2(rb.w, bv[6], bv[7]);
        }
        float w = wdec[t];
        #pragma unroll
        for (int i = 0; i < 8; ++i) {
            int o = tsw(e + i, 2 * t);
            unsigned short hh, ll;
            split_bf(xv[i], hh, ll);
            *(unsigned short*)(XThb + o) = hh;
            *(unsigned short*)(XTlb + o) = ll;
            split_bf(bv[i] * w, hh, ll);
            *(unsigned short*)(BThb + o) = hh;
            *(unsigned short*)(BTlb + o) = ll;
        }
    }
    __syncthreads();

    const int l = tid & 63, w4 = tid >> 6;
    const int lr = l & 15, q = l >> 4;
    const int rowA = 16 * w4 + lr;

    const int oa0 = tsw(rowA, 16 * q);
    const int oa1 = tsw(rowA, 16 * q + 64);
    bf16x8 a0h = *(const bf16x8*)(XThb + oa0);
    bf16x8 a1h = *(const bf16x8*)(XThb + oa1);
    bf16x8 a0l = *(const bf16x8*)(XTlb + oa0);
    bf16x8 a1l = *(const bf16x8*)(XTlb + oa1);

    f32x4 acc[4];
    #pragma unroll
    for (int nt = 0; nt < 4; ++nt) acc[nt] = (f32x4){0.f, 0.f, 0.f, 0.f};
    #pragma unroll
    for (int nt = 0; nt < 4; ++nt) {
        int ob0 = tsw(16 * nt + lr, 16 * q);
        int ob1 = tsw(16 * nt + lr, 16 * q + 64);
        bf16x8 b0h = *(const bf16x8*)(BThb + ob0);
        bf16x8 b0l = *(const bf16x8*)(BTlb + ob0);
        bf16x8 b1h = *(const bf16x8*)(BThb + ob1);
        bf16x8 b1l = *(const bf16x8*)(BTlb + ob1);
        acc[nt] = __builtin_amdgcn_mfma_f32_16x16x32_bf16(a0h, b0h, acc[nt], 0, 0, 0);
        acc[nt] = __builtin_amdgcn_mfma_f32_16x16x32_bf16(a1h, b1h, acc[nt], 0, 0, 0);
        acc[nt] = __builtin_amdgcn_mfma_f32_16x16x32_bf16(a0h, b0l, acc[nt], 0, 0, 0);
        acc[nt] = __builtin_amdgcn_mfma_f32_16x16x32_bf16(a1h, b1l, acc[nt], 0, 0, 0);
        acc[nt] = __builtin_amdgcn_mfma_f32_16x16x32_bf16(a0l, b0h, acc[nt], 0, 0, 0);
        acc[nt] = __builtin_amdgcn_mfma_f32_16x16x32_bf16(a1l, b1h, acc[nt], 0, 0, 0);
    }

    float* sp = states + (size_t)((b * C_ + c) * H_ + h) * 4096;
    #pragma unroll
    for (int nt = 0; nt < 4; ++nt)
        #pragma unroll
        for (int r = 0; r < 4; ++r) {
            int p = 16 * w4 + 4 * q + r;
            int n = 16 * nt + lr;
            sp[p * 64 + n] = acc[nt][r];
        }
}

// ---------------------------------------------------------------------------
// K2: inter-chunk scan, in place. 512 blocks, float2 chains, next-chunk
// prefetch. Layout-agnostic across the 4096 state elements.
// ---------------------------------------------------------------------------
__global__ __launch_bounds__(256) void k2_scan(
    float* __restrict__ states, const float* __restrict__ sums)
{
    const int tid = threadIdx.x;
    const int bid = blockIdx.x;
    const int split = bid & 7;
    const int bh = bid >> 3;
    const int h = bh & 31;
    const int b = bh >> 5;
    const int e = split * 512 + tid * 2;
    const float* sm = sums + (b * H_ + h) * C_;
    const size_t cstride = (size_t)H_ * 4096;
    float* p = states + ((size_t)(b * C_) * H_ + h) * 4096 + e;
    float2 S = make_float2(0.f, 0.f);
    float2 st = *(const float2*)p;
    #pragma unroll 4
    for (int c = 0; c < 64; ++c) {
        float2 stn = make_float2(0.f, 0.f);
        if (c < 63) stn = *(const float2*)(p + cstride);   // prefetch next chunk
        float d = __expf(sm[c]);
        *(float2*)p = S;          // S_enter[c]
        S.x = S.x * d + st.x;
        S.y = S.y * d + st.y;
        st = stn;
        p += cstride;
    }
}

// ---------------------------------------------------------------------------
// K3 (unified, split-bf16 MFMA):
//   MFMA#1: M = C·B^T   (contract n; C,B natural [t][n] hi/lo, nsw)
//   MFMA#3: Yoff = C·S  (contract n; S natural [p][n] hi/lo, nsw) -> own acc
//   barrier; write M (mask+decay, fp32->hi/lo) over B region;
//            scatter X^T [p][s] hi/lo over S region (tsw; X preloaded to regs)
//   MFMA#2: Ydiag = M·X (contract s)
//   epilogue: Y = Ydiag + exp(cs[t])·Yoff (fp32-exact scale), dtype store.
// LDS = 6 x 8KB + 256B -> 3 blocks/CU.
// ---------------------------------------------------------------------------
__global__ __launch_bounds__(256, 3) void k3u(
    const void* __restrict__ Xg,
    const void* __restrict__ Ag,
    const void* __restrict__ Bg,
    const void* __restrict__ Cg,
    const float* __restrict__ states,
    void* __restrict__ Yg,
    const int* __restrict__ flag)
{
    __shared__ __align__(16) unsigned short Ch[4096];
    __shared__ __align__(16) unsigned short Cl[4096];
    __shared__ __align__(16) unsigned short Bh[4096];
    __shared__ __align__(16) unsigned short Bl[4096];
    __shared__ __align__(16) unsigned short Sh[4096];
    __shared__ __align__(16) unsigned short Sl[4096];
    __shared__ float csh[64];

    const int tid = threadIdx.x;
    const int bid = blockIdx.x;
    const int h = bid & 31, c = (bid >> 5) & 63, b = bid >> 11;
    const int isf32 = *flag;

    if (tid < 64) {
        int ai = (b * S_ + c * 64 + tid) * H_ + h;
        float a = isf32 ? ((const float*)Ag)[ai] : bf2f(((const unsigned short*)Ag)[ai]);
        float x = a;
        #pragma unroll
        for (int off = 1; off < 64; off <<= 1) {
            float y = __shfl_up(x, off, 64);
            if (tid >= off) x += y;
        }
        csh[tid] = x;
    }

    const size_t baseX = (size_t)((b * S_ + c * 64) * H_ + h) * P_;
    const size_t baseN = (size_t)((b * S_ + c * 64) * H_ + h) * N_;
    char* Chb = (char*)Ch; char* Clb = (char*)Cl;
    char* Bhb = (char*)Bh; char* Blb = (char*)Bl;
    char* Shb = (char*)Sh; char* Slb = (char*)Sl;

    // preload X into registers (consumed after barrier2; latency hides
    // under staging + MFMA#1/#3)
    uint4 xq0[2], xq1[2];
    #pragma unroll
    for (int it = 0; it < 2; ++it) {
        int t = (tid >> 3) + it * 32;
        int e = (tid & 7) * 8;
        if (isf32) {
            const float* Xp = (const float*)Xg + baseX + (size_t)t * HP + e;
            xq0[it] = *(const uint4*)Xp;
            xq1[it] = *(const uint4*)(Xp + 4);
        } else {
            const unsigned short* Xp = (const unsigned short*)Xg + baseX + (size_t)t * HP + e;
            xq0[it] = *(const uint4*)Xp;
        }
    }

    // stage C and B (natural hi/lo)
    #pragma unroll
    for (int it = 0; it < 2; ++it) {
        int t = (tid >> 3) + it * 32;
        int e = (tid & 7) * 8;
        float cv[8], bv[8];
        if (isf32) {
            const float* Cp = (const float*)Cg + baseN + (size_t)t * HN + e;
            const float* Bp = (const float*)Bg + baseN + (size_t)t * HN + e;
            float4 c0 = *(const float4*)Cp;
            float4 c1 = *(const float4*)(Cp + 4);
            float4 b0 = *(const float4*)Bp;
            float4 b1 = *(const float4*)(Bp + 4);
            cv[0]=c0.x; cv[1]=c0.y; cv[2]=c0.z; cv[3]=c0.w;
            cv[4]=c1.x; cv[5]=c1.y; cv[6]=c1.z; cv[7]=c1.w;
            bv[0]=b0.x; bv[1]=b0.y; bv[2]=b0.z; bv[3]=b0.w;
            bv[4]=b1.x; bv[5]=b1.y; bv[6]=b1.z; bv[7]=b1.w;
        } else {
            const unsigned short* Cp = (const unsigned short*)Cg + baseN + (size_t)t * HN + e;
            const unsigned short* Bp = (const unsigned short*)Bg + baseN + (size_t)t * HN + e;
            uint4 rc = *(const uint4*)Cp;
            uint4 rb = *(const uint4*)Bp;
            unpack2(rc.x, cv[0], cv[1]); unpack2(rc.y, cv[2], cv[3]);
            unpack2(rc.z, cv[4], cv[5]); unpack2(rc.w, cv[6], cv[7]);
            unpack2(rb.x, bv[0], bv[1]); unpack2(rb.y, bv[2], bv[3]);
            unpack2(rb.z, bv[4], bv[5]); unpack2(rb.w, bv[6], bv[7]);
        }
        int o = nsw(t, 2 * e);
        unsigned short hs[8], ls[8];
        #pragma unroll
        for (int i = 0; i < 8; ++i) split_bf(cv[i], hs[i], ls[i]);
        {
            uint4 uh, ul;
            uh.x = (unsigned int)hs[0] | ((unsigned int)hs[1] << 16);
            uh.y = (unsigned int)hs[2] | ((unsigned int)hs[3] << 16);
            uh.z = (unsigned int)hs[4] | ((unsigned int)hs[5] << 16);
            uh.w = (unsigned int)hs[6] | ((unsigned int)hs[7] << 16);
            ul.x = (unsigned int)ls[0] | ((unsigned int)ls[1] << 16);
            ul.y = (unsigned int)ls[2] | ((unsigned int)ls[3] << 16);
            ul.z = (unsigned int)ls[4] | ((unsigned int)ls[5] << 16);
            ul.w = (unsigned int)ls[6] | ((unsigned int)ls[7] << 16);
            *(uint4*)(Chb + o) = uh;
            *(uint4*)(Clb + o) = ul;
        }
        #pragma unroll
        for (int i = 0; i < 8; ++i) split_bf(bv[i], hs[i], ls[i]);
        {
            uint4 uh, ul;
            uh.x = (unsigned int)hs[0] | ((unsigned int)hs[1] << 16);
            uh.y = (unsigned int)hs[2] | ((unsigned int)hs[3] << 16);
            uh.z = (unsigned int)hs[4] | ((unsigned int)hs[5] << 16);
            uh.w = (unsigned int)hs[6] | ((unsigned int)hs[7] << 16);
            ul.x = (unsigned int)ls[0] | ((unsigned int)ls[1] << 16);
            ul.y = (unsigned int)ls[2] | ((unsigned int)ls[3] << 16);
            ul.z = (unsigned int)ls[4] | ((unsigned int)ls[5] << 16);
            ul.w = (unsigned int)ls[6] | ((unsigned int)ls[7] << 16);
            *(uint4*)(Bhb + o) = uh;
            *(uint4*)(Blb + o) = ul;
        }
    }

    // stage S_enter [p][n] (fp32 workspace) as hi/lo
    {
        const float* sb = states + (size_t)((b * C_ + c) * H_ + h) * 4096;
        #pragma unroll
        for (int k = 0; k < 4; ++k) {
            int e2 = (k * 256 + tid) * 4;
            float4 v = *(const float4*)(sb + e2);
            unsigned short h0,l0,h1,l1,h2,l2,h3,l3;
            split_bf(v.x, h0, l0); split_bf(v.y, h1, l1);
            split_bf(v.z, h2, l2); split_bf(v.w, h3, l3);
            uint2 uh, ul;
            uh.x = (unsigned int)h0 | ((unsigned int)h1 << 16);
            uh.y = (unsigned int)h2 | ((unsigned int)h3 << 16);
            ul.x = (unsigned int)l0 | ((unsigned int)l1 << 16);
            ul.y = (unsigned int)l2 | ((unsigned int)l3 << 16);
            int o = nsw(e2 >> 6, 2 * (e2 & 63));
            *(uint2*)(Shb + o) = uh;
            *(uint2*)(Slb + o) = ul;
        }
    }
    __syncthreads();

    const int l = tid & 63, w4 = tid >> 6;
    const int lr = l & 15, q = l >> 4;
    const int tA = 16 * w4 + lr;     // this lane's A-fragment row

    const int oa0 = nsw(tA, 16 * q);
    const int oa1 = nsw(tA, 16 * q + 64);
    bf16x8 ac0h = *(const bf16x8*)(Chb + oa0);
    bf16x8 ac1h = *(const bf16x8*)(Chb + oa1);
    bf16x8 ac0l = *(const bf16x8*)(Clb + oa0);
    bf16x8 ac1l = *(const bf16x8*)(Clb + oa1);

    // MFMA#1: M = C·B^T
    f32x4 mac[4];
    #pragma unroll
    for (int st = 0; st < 4; ++st) mac[st] = (f32x4){0.f, 0.f, 0.f, 0.f};
    #pragma unroll
    for (int st = 0; st < 4; ++st) {
        int ob0 = nsw(16 * st + lr, 16 * q);
        int ob1 = nsw(16 * st + lr, 16 * q + 64);
        bf16x8 b0h = *(const bf16x8*)(Bhb + ob0);
        bf16x8 b0l = *(const bf16x8*)(Blb + ob0);
        bf16x8 b1h = *(const bf16x8*)(Bhb + ob1);
        bf16x8 b1l = *(const bf16x8*)(Blb + ob1);
        mac[st] = __builtin_amdgcn_mfma_f32_16x16x32_bf16(ac0h, b0h, mac[st], 0, 0, 0);
        mac[st] = __builtin_amdgcn_mfma_f32_16x16x32_bf16(ac1h, b1h, mac[st], 0, 0, 0);
        mac[st] = __builtin_amdgcn_mfma_f32_16x16x32_bf16(ac0h, b0l, mac[st], 0, 0, 0);
        mac[st] = __builtin_amdgcn_mfma_f32_16x16x32_bf16(ac1h, b1l, mac[st], 0, 0, 0);
        mac[st] = __builtin_amdgcn_mfma_f32_16x16x32_bf16(ac0l, b0h, mac[st], 0, 0, 0);
        mac[st] = __builtin_amdgcn_mfma_f32_16x16x32_bf16(ac1l, b1h, mac[st], 0, 0, 0);
    }

    // MFMA#3: Yoff = C·S (separate accumulator; exp(cs) applied in epilogue)
    f32x4 yacO[4];
    #pragma unroll
    for (int pt = 0; pt < 4; ++pt) yacO[pt] = (f32x4){0.f, 0.f, 0.f, 0.f};
    #pragma unroll
    for (int pt = 0; pt < 4; ++pt) {
        int os0 = nsw(16 * pt + lr, 16 * q);
        int os1 = nsw(16 * pt + lr, 16 * q + 64);
        bf16x8 s0h = *(const bf16x8*)(Shb + os0);
        bf16x8 s0l = *(const bf16x8*)(Slb + os0);
        bf16x8 s1h = *(const bf16x8*)(Shb + os1);
        bf16x8 s1l = *(const bf16x8*)(Slb + os1);
        yacO[pt] = __builtin_amdgcn_mfma_f32_16x16x32_bf16(ac0h, s0h, yacO[pt], 0, 0, 0);
        yacO[pt] = __builtin_amdgcn_mfma_f32_16x16x32_bf16(ac1h, s1h, yacO[pt], 0, 0, 0);
        yacO[pt] = __builtin_amdgcn_mfma_f32_16x16x32_bf16(ac0h, s0l, yacO[pt], 0, 0, 0);
        yacO[pt] = __builtin_amdgcn_mfma_f32_16x16x32_bf16(ac1h, s1l, yacO[pt], 0, 0, 0);
        yacO[pt] = __builtin_amdgcn_mfma_f32_16x16x32_bf16(ac0l, s0h, yacO[pt], 0, 0, 0);
        yacO[pt] = __builtin_amdgcn_mfma_f32_16x16x32_bf16(ac1l, s1h, yacO[pt], 0, 0, 0);
    }
    __syncthreads();   // all waves done reading B and S regions

    // write M (mask + segment decay, fp32 -> hi/lo) over B region
    float ct[4];
    #pragma unroll
    for (int r = 0; r < 4; ++r) ct[r] = csh[16 * w4 + 4 * q + r];
    #pragma unroll
    for (int st = 0; st < 4; ++st) {
        int s = 16 * st + lr;
        float cs_s = csh[s];
        #pragma unroll
        for (int r = 0; r < 4; ++r) {
            int t = 16 * w4 + 4 * q + r;
            float v = (s <= t) ? mac[st][r] * __expf(ct[r] - cs_s) : 0.f;
            unsigned short hh, ll;
            split_bf(v, hh, ll);
            int o = nsw(t, 2 * s);
            *(unsigned short*)(Bhb + o) = hh;
            *(unsigned short*)(Blb + o) = ll;
        }
    }

    // scatter X^T [p][s] hi/lo over S region (from preloaded registers)
    #pragma unroll
    for (int it = 0; it < 2; ++it) {
        int t = (tid >> 3) + it * 32;
        int e = (tid & 7) * 8;
        float xv[8];
        if (isf32) {
            xv[0] = __uint_as_float(xq0[it].x); xv[1] = __uint_as_float(xq0[it].y);
            xv[2] = __uint_as_float(xq0[it].z); xv[3] = __uint_as_float(xq0[it].w);
            xv[4] = __uint_as_float(xq1[it].x); xv[5] = __uint_as_float(xq1[it].y);
            xv[6] = __uint_as_float(xq1[it].z); xv[7] = __uint_as_float(xq1[it].w);
        } else {
            unpack2(xq0[it].x, xv[0], xv[1]); unpack2(xq0[it].y, xv[2], xv[3]);
            unpack2(xq0[it].z, xv[4], xv[5]); unpack2(xq0[it].w, xv[6], xv[7]);
        }
        #pragma unroll
        for (int i = 0; i < 8; ++i) {
            unsigned short hh, ll;
            split_bf(xv[i], hh, ll);
            int o = tsw(e + i, 2 * t);
            *(unsigned short*)(Shb + o) = hh;
            *(unsigned short*)(Slb + o) = ll;
        }
    }
    __syncthreads();

    // MFMA#2: Ydiag = M·X
    const int om0 = nsw(tA, 16 * q);
    const int om1 = nsw(tA, 16 * q + 64);
    bf16x8 am0h = *(const bf16x8*)(Bhb + om0);
    bf16x8 am1h = *(const bf16x8*)(Bhb + om1);
    bf16x8 am0l = *(const bf16x8*)(Blb + om0);
    bf16x8 am1l = *(const bf16x8*)(Blb + om1);
    f32x4 yacD[4];
    #pragma unroll
    for (int pt = 0; pt < 4; ++pt) yacD[pt] = (f32x4){0.f, 0.f, 0.f, 0.f};
    #pragma unroll
    for (int pt = 0; pt < 4; ++pt) {
        int ox0 = tsw(16 * pt + lr, 16 * q);
        int ox1 = tsw(16 * pt + lr, 16 * q + 64);
        bf16x8 x0h = *(const bf16x8*)(Shb + ox0);
        bf16x8 x0l = *(const bf16x8*)(Slb + ox0);
        bf16x8 x1h = *(const bf16x8*)(Shb + ox1);
        bf16x8 x1l = *(const bf16x8*)(Slb + ox1);
        yacD[pt] = __builtin_amdgcn_mfma_f32_16x16x32_bf16(am0h, x0h, yacD[pt], 0, 0, 0);
        yacD[pt] = __builtin_amdgcn_mfma_f32_16x16x32_bf16(am1h, x1h, yacD[pt], 0, 0, 0);
        yacD[pt] = __builtin_amdgcn_mfma_f32_16x16x32_bf16(am0h, x0l, yacD[pt], 0, 0, 0);
        yacD[pt] = __builtin_amdgcn_mfma_f32_16x16x32_bf16(am1h, x1l, yacD[pt], 0, 0, 0);
        yacD[pt] = __builtin_amdgcn_mfma_f32_16x16x32_bf16(am0l, x0h, yacD[pt], 0, 0, 0);
        yacD[pt] = __builtin_amdgcn_mfma_f32_16x16x32_bf16(am1l, x1h, yacD[pt], 0, 0, 0);
    }

    // epilogue: Y[t][p] = Ydiag + exp(cs[t]) * Yoff
    float ge[4];
    #pragma unroll
    for (int r = 0; r < 4; ++r) ge[r] = __expf(ct[r]);
    if (!isf32) {
        unsigned short* Yp = (unsigned short*)Yg + baseX;
        #pragma unroll
        for (int pt = 0; pt < 4; ++pt)
            #pragma unroll
            for (int r = 0; r < 4; ++r) {
                int t = 16 * w4 + 4 * q + r;
                Yp[(size_t)t * HP + 16 * pt + lr] = f2bf(yacD[pt][r] + ge[r] * yacO[pt][r]);
            }
    } else {
        float* Yp = (float*)Yg + baseX;
        #pragma unroll
        for (int pt = 0; pt < 4; ++pt)
            #pragma unroll
            for (int r = 0; r < 4; ++r) {
                int t = 16 * w4 + 4 * q + r;
                Yp[(size_t)t * HP + 16 * pt + lr] = yacD[pt][r] + ge[r] * yacO[pt][r];
            }
    }
}

extern "C" void kernel_launch(void* const* d_in, const int* in_sizes, int n_in,
                              void* d_out, int out_size, void* d_ws, size_t ws_size,
                              hipStream_t stream) {
    const void* X  = d_in[0];
    const void* A  = d_in[1];
    const void* Bm = d_in[2];
    const void* Cm = d_in[3];

    // ws layout: [0..15] flag int (16B), then sums (4096 f), then states (16M f)
    int*   flag   = (int*)d_ws;
    float* sums   = (float*)d_ws + 16;
    float* states = (float*)d_ws + 16 + 4096;

    k0_detect<<<dim3(1), dim3(64), 0, stream>>>((const unsigned short*)A, flag);
    k1u<<<dim3(B_ * C_ * H_), dim3(256), 0, stream>>>(X, A, Bm, states, sums, flag);
    k2_scan<<<dim3(B_ * H_ * 8), dim3(256), 0, stream>>>(states, sums);
    k3u<<<dim3(B_ * C_ * H_), dim3(256), 0, stream>>>(X, A, Bm, Cm, states, d_out, flag);
}